// Round 7
// baseline (103.002 us; speedup 1.0000x reference)
//
#include <hip/hip_runtime.h>

// RealtimeNgramProcessor R7: 2 dispatches total.
//   build_all: no memset/scatter — every table entry computed by binary search.
//     d2[i]   (u16, 2^18 entries, 512 KB): bigram val or 0.
//     meta[b] (u32, 2^17 entries, 512 KB): (start<<11)|count for sorted keys3
//             buckets of 1024 key values (start<2^21, count<=1024 fit).
//   main8: 8 elems/thread, 16 independent gathers in flight (ILP),
//          69% of trigram buckets empty -> 1 load and done.
// Tables rebuilt every launch (harness re-poisons ws; same work per call).

#define TOKEN_VOCAB 512
#define D2_ENTRIES (1 << 18)          // bigram key space
#define SHIFT3 10
#define NBUCKET3 (1 << 17)            // key3 < 2^27, buckets of 2^10

__device__ __forceinline__ int lower_bound_dev(const int* __restrict__ a,
                                               int n, int target) {
    int lo = 0, hi = n;
    while (lo < hi) {
        int mid = (lo + hi) >> 1;
        if (a[mid] < target) lo = mid + 1; else hi = mid;
    }
    return lo;
}

__global__ void __launch_bounds__(256)
build_all(const int* __restrict__ keys2, const int* __restrict__ vals2, int K2,
          const int* __restrict__ keys3, int K3,
          unsigned short* __restrict__ d2, unsigned* __restrict__ meta) {
    int i = blockIdx.x * blockDim.x + threadIdx.x;
    if (i < D2_ENTRIES) {
        int lo = lower_bound_dev(keys2, K2, i);
        unsigned short v = 0;
        if (lo < K2 && keys2[lo] == i) v = (unsigned short)vals2[lo];
        d2[i] = v;
    }
    if (i < NBUCKET3) {
        int lo = lower_bound_dev(keys3, K3, i << SHIFT3);
        int hi = lower_bound_dev(keys3, K3, (i + 1) << SHIFT3);
        meta[i] = ((unsigned)lo << 11) | (unsigned)(hi - lo);
    }
}

__global__ void __launch_bounds__(256)
main8(const int* __restrict__ x,
      const unsigned short* __restrict__ d2,
      const unsigned* __restrict__ meta,
      const int* __restrict__ keys3,
      const int* __restrict__ vals3,
      int* __restrict__ out, int total, int S) {
    int base = (blockIdx.x * blockDim.x + threadIdx.x) * 8;
    if (base >= total) return;
    int s = base & (S - 1);                   // base%8==0; s==0 -> row start
    const int4 ca = *(const int4*)(x + base);
    const int4 cb = *(const int4*)(x + base + 4);
    int tm1 = (s >= 1) ? x[base - 1] : 0;     // left pad 0
    int tm2 = (s >= 1) ? x[base - 2] : 0;
    int t[10] = {tm2, tm1, ca.x, ca.y, ca.z, ca.w, cb.x, cb.y, cb.z, cb.w};

    int o2[8], k3v[8];
    unsigned m[8];
    #pragma unroll
    for (int j = 0; j < 8; ++j) {             // 16 independent loads in flight
        int k2 = t[j + 1] * TOKEN_VOCAB + t[j + 2];
        int k3 = (t[j] * TOKEN_VOCAB + t[j + 1]) * TOKEN_VOCAB + t[j + 2];
        k3v[j] = k3;
        o2[j] = (int)d2[k2];
        m[j] = meta[k3 >> SHIFT3];
    }
    int o3[8];
    #pragma unroll
    for (int j = 0; j < 8; ++j) {
        int v = 0;
        int cnt = (int)(m[j] & 2047u);
        if (cnt) {                            // ~31% of elements
            int p = (int)(m[j] >> 11);
            for (int e = 0; e < cnt; ++e) {   // sorted, avg ~1.2 iter
                int kv = keys3[p + e];
                if (kv >= k3v[j]) { if (kv == k3v[j]) v = vals3[p + e]; break; }
            }
        }
        o3[j] = v;
    }
    *(int4*)(out + base)             = make_int4(o2[0], o2[1], o2[2], o2[3]);
    *(int4*)(out + base + 4)         = make_int4(o2[4], o2[5], o2[6], o2[7]);
    *(int4*)(out + total + base)     = make_int4(o3[0], o3[1], o3[2], o3[3]);
    *(int4*)(out + total + base + 4) = make_int4(o3[4], o3[5], o3[6], o3[7]);
}

// Fallback (ws too small): plain binary search per element (R1, verified).
__device__ __forceinline__ int table_lookup(const int* __restrict__ keys,
                                            const int* __restrict__ vals,
                                            int K, int packed) {
    int lo = 0, hi = K;
    while (lo < hi) {
        int mid = (lo + hi) >> 1;
        if (keys[mid] < packed) lo = mid + 1; else hi = mid;
    }
    int pos = lo < (K - 1) ? lo : (K - 1);
    return (keys[pos] == packed) ? vals[pos] : 0;
}

__global__ void ngram_encode_kernel(const int* __restrict__ x,
                                    const int* __restrict__ keys2,
                                    const int* __restrict__ vals2, int K2,
                                    const int* __restrict__ keys3,
                                    const int* __restrict__ vals3, int K3,
                                    int* __restrict__ out, int total, int S) {
    int idx = blockIdx.x * blockDim.x + threadIdx.x;
    if (idx >= total) return;
    int s = idx & (S - 1);
    int t0 = x[idx];
    int t1 = (s >= 1) ? x[idx - 1] : 0;
    int t2 = (s >= 2) ? x[idx - 2] : 0;
    int k2 = t1 * TOKEN_VOCAB + t0;
    int k3 = (t2 * TOKEN_VOCAB + t1) * TOKEN_VOCAB + t0;
    out[idx]         = table_lookup(keys2, vals2, K2, k2);
    out[total + idx] = table_lookup(keys3, vals3, K3, k3);
}

extern "C" void kernel_launch(void* const* d_in, const int* in_sizes, int n_in,
                              void* d_out, int out_size, void* d_ws, size_t ws_size,
                              hipStream_t stream) {
    const int* x     = (const int*)d_in[0];
    const int* keys2 = (const int*)d_in[1];
    const int* vals2 = (const int*)d_in[2];
    const int* keys3 = (const int*)d_in[3];
    const int* vals3 = (const int*)d_in[4];
    int* out = (int*)d_out;

    const int total = in_sizes[0];            // 256*8192 = 2097152
    const int S = 8192;
    const int K2 = in_sizes[1];
    const int K3 = in_sizes[3];

    // ws layout: d2 u16 [2^18] (512 KB) | meta u32 [2^17] (512 KB)
    unsigned short* d2   = (unsigned short*)d_ws;
    unsigned*       meta = (unsigned*)(d2 + D2_ENTRIES);
    const size_t ws_needed = (size_t)D2_ENTRIES * 2 + (size_t)NBUCKET3 * 4;

    if (ws_size >= ws_needed) {
        build_all<<<(D2_ENTRIES + 255) / 256, 256, 0, stream>>>(
            keys2, vals2, K2, keys3, K3, d2, meta);
        const int threads_main = total / 8;   // 262144
        main8<<<(threads_main + 255) / 256, 256, 0, stream>>>(
            x, d2, meta, keys3, vals3, out, total, S);
    } else {
        ngram_encode_kernel<<<(total + 255) / 256, 256, 0, stream>>>(
            x, keys2, vals2, K2, keys3, vals3, K3, out, total, S);
    }
}